// Round 14
// baseline (1541.973 us; speedup 1.0000x reference)
//
#include <hip/hip_runtime.h>

// TopK-and-scatter: out[r,c] = x[r,c] if x[r,c] is among the top-64 of row r
// (ties at threshold broken by LOWEST column index, matching lax.top_k), else 0.
// R14: TWO-KERNEL split to remove phase structure from the streaming work.
// K1 (no barriers/LDS/phases): grid-stride stream of the full input; writes
// zeros to out, appends elements with (int)bits > bits(2.0f) (positives only;
// any 64 such elements outrank everything <= 2.0) to per-row global candidate
// lists in d_ws (packed (bits<<32)|~col, global atomic counter per row).
// K2 (tiny): per row, load ~750 candidates to LDS, mini-hist -> suffix scan ->
// exact packed-key rank of crossing bin -> scatter <=64 dwords over K1's zeros.
// Counters zeroed by hipMemsetAsync (stream-ordered). Exact slow path in K2
// (C<64 / C>cap / fat bin) re-streams the row; never taken for N(0,1) data
// (count(x>2) in [~646,~844], cap 1024). If ws_size < 64 MB, host falls back
// to the proven R13 single-kernel (included verbatim below).

typedef unsigned int u32;
typedef unsigned long long u64;
typedef u32 u32x4 __attribute__((ext_vector_type(4)));

#define COLS   32768
#define KSEL   64u
#define THR    0x40000000u  // bits of 2.0f
#define CAPW   1024u        // per-row candidate capacity in d_ws
#define EQCAP  256u

__device__ __forceinline__ u32 toKey(u32 b) {
    return b ^ ((u32)((int)b >> 31) | 0x80000000u);
}

// ---------------- Kernel 1: barrier-free stream + compact ----------------
__global__ __launch_bounds__(256) void stream_compact_kernel(
    const u32x4* __restrict__ x, u32x4* __restrict__ out,
    u32* __restrict__ cnt, u64* __restrict__ lists, u32 totalVec)
{
    const u32 stride = gridDim.x * 256u;
    for (u32 v0 = blockIdx.x * 256u + threadIdx.x; v0 < totalVec; v0 += stride * 8u) {
        u32x4 d[8];
        u32   vi[8];
        #pragma unroll
        for (int j = 0; j < 8; ++j) {
            const u32 v = v0 + (u32)j * stride;
            vi[j] = v;
            if (v < totalVec) d[j] = x[v];
        }
        #pragma unroll
        for (int j = 0; j < 8; ++j)
            if (vi[j] < totalVec) out[vi[j]] = (u32x4)(0u);
        #pragma unroll
        for (int j = 0; j < 8; ++j) {
            const u32 v = vi[j];
            if (v < totalVec) {
                const u32 row = v >> 13;                 // 8192 vectors per row
                #pragma unroll
                for (int l = 0; l < 4; ++l) {
                    const u32 k = d[j][l];
                    if ((int)k > (int)THR) {
                        const u32 p = atomicAdd(&cnt[row], 1u);
                        if (p < CAPW) {
                            const u32 col = (v & 8191u) * 4u + (u32)l;
                            lists[(u64)row * CAPW + p] =
                                ((u64)k << 32) | (u32)(~col);
                        }
                    }
                }
            }
        }
    }
}

// ---------------- Kernel 2: per-row select + scatter ----------------
__global__ __launch_bounds__(256) void select_scatter_kernel(
    const u32x4* __restrict__ x, float* __restrict__ out,
    const u32* __restrict__ cnt, const u64* __restrict__ lists)
{
    __shared__ u64 cpk[CAPW];             // 8 KB
    __shared__ u64 eqPk[EQCAP];           // 2 KB
    __shared__ u32 hist[1024];            // 4 KB
    __shared__ u32 wtot[4];
    __shared__ int sBin;
    __shared__ u32 sAbove, sEqCnt, eqN;

    const int tid  = threadIdx.x;
    const int lane = tid & 63;
    const int wid  = tid >> 6;
    const u32 row  = blockIdx.x;

    u32* __restrict__ orowU = (u32*)(out + (u64)row * COLS);
    const u32x4* __restrict__ xrow = x + (u64)row * (COLS / 4);

    const u32 C = cnt[row];
    ((u32x4*)hist)[tid] = (u32x4)(0u);
    if (tid == 0) { sBin = -1; eqN = 0u; }

    bool fastOk = (C >= KSEL && C <= CAPW);
    if (fastOk) {
        // load candidates to LDS (coalesced) + mini histogram
        for (u32 i = tid; i < C; i += 256u) {
            const u64 pk = lists[(u64)row * CAPW + i];
            cpk[i] = pk;
        }
        __syncthreads();                   // A: cpk + hist zeros ready
        for (u32 i = tid; i < C; i += 256u) {
            const u32 k = (u32)(cpk[i] >> 32);
            u32 idx = (k - THR) >> 15;
            if (idx > 1023u) idx = 1023u;
            atomicAdd(&hist[idx], 1u);
        }
        __syncthreads();                   // B: hist ready
        // suffix scan: thread owns bins [4*tid, 4*tid+4)
        {
            const u32x4 h = ((const u32x4*)hist)[tid];
            const u32 ls3 = h[3];
            const u32 ls2 = h[2] + ls3;
            const u32 ls1 = h[1] + ls2;
            const u32 ls0 = h[0] + ls1;
            u32 v = ls0;
            #pragma unroll
            for (int off = 1; off < 64; off <<= 1) {
                const u32 t = __shfl_down(v, off);
                if (lane + off < 64) v += t;
            }
            if (lane == 0) wtot[wid] = v;
            __syncthreads();               // C: wtot ready
            u32 tail = 0u;
            #pragma unroll
            for (int w = 0; w < 4; ++w) if (w > wid) tail += wtot[w];
            const u32 thrTail = tail + (v - ls0);
            const u32 S0 = ls0 + thrTail, S1 = ls1 + thrTail,
                      S2 = ls2 + thrTail, S3 = ls3 + thrTail, S4 = thrTail;
            if (S0 >= KSEL && S1 < KSEL) { sBin = 4*tid+0; sAbove = S1; sEqCnt = h[0]; }
            if (S1 >= KSEL && S2 < KSEL) { sBin = 4*tid+1; sAbove = S2; sEqCnt = h[1]; }
            if (S2 >= KSEL && S3 < KSEL) { sBin = 4*tid+2; sAbove = S3; sEqCnt = h[2]; }
            if (S3 >= KSEL && S4 < KSEL) { sBin = 4*tid+3; sAbove = S4; sEqCnt = h[3]; }
            __syncthreads();               // D: crossing known (C >= KSEL)
        }
        const u32 b1     = (u32)sBin;
        const u32 need   = KSEL - sAbove;
        const u32 binCnt = sEqCnt;
        if (binCnt <= EQCAP) {
            for (u32 i = tid; i < C; i += 256u) {
                const u32 k = (u32)(cpk[i] >> 32);
                u32 idx = (k - THR) >> 15;
                if (idx > 1023u) idx = 1023u;
                if (idx == b1) { const u32 p = atomicAdd(&eqN, 1u); eqPk[p] = cpk[i]; }
            }
            __syncthreads();               // E: eq list ready
            const u32 E2 = eqN;
            for (u32 i = tid; i < C; i += 256u) {
                const u64 pk = cpk[i];
                const u32 k  = (u32)(pk >> 32);
                u32 idx = (k - THR) >> 15;
                if (idx > 1023u) idx = 1023u;
                bool sel = (idx > b1);
                if (idx == b1) {
                    u32 r = 0;
                    for (u32 q = 0; q < E2; ++q) r += (eqPk[q] > pk) ? 1u : 0u;
                    sel = (r < need);
                }
                if (sel) orowU[~(u32)pk] = k;
            }
            return;
        }
        fastOk = false;
    }

    // ---- exact slow path: streaming bitwise searches + scatter ----
    {
        u32 pfx = 0u;
        for (int bit = 31; bit >= 0; --bit) {
            const u32 trial = pfx | (1u << bit);
            u32 loc = 0u;
            #pragma unroll 1
            for (int m = 0; m < 32; ++m) {
                const u32x4 v = xrow[m * 256 + tid];
                #pragma unroll
                for (int l = 0; l < 4; ++l) loc += (toKey(v[l]) >= trial) ? 1u : 0u;
            }
            #pragma unroll
            for (int off = 32; off >= 1; off >>= 1) loc += __shfl_down(loc, off);
            if (lane == 0) wtot[wid] = loc;
            __syncthreads();
            u32 t = 0;
            #pragma unroll
            for (int w = 0; w < 4; ++w) t += wtot[w];
            __syncthreads();
            if (t >= KSEL) pfx = trial;
        }
        const u32 T = pfx;
        u32 loc = 0u;
        #pragma unroll 1
        for (int m = 0; m < 32; ++m) {
            const u32x4 v = xrow[m * 256 + tid];
            #pragma unroll
            for (int l = 0; l < 4; ++l) loc += (toKey(v[l]) > T) ? 1u : 0u;
        }
        #pragma unroll
        for (int off = 32; off >= 1; off >>= 1) loc += __shfl_down(loc, off);
        if (lane == 0) wtot[wid] = loc;
        __syncthreads();
        u32 above = 0;
        #pragma unroll
        for (int w = 0; w < 4; ++w) above += wtot[w];
        __syncthreads();
        const u32 needEq = KSEL - above;
        u32 cv = 0u;
        for (int bit = 14; bit >= 0; --bit) {
            const u32 trial = cv | (1u << bit);
            u32 l2 = 0u;
            #pragma unroll 1
            for (int m = 0; m < 32; ++m) {
                const u32x4 v = xrow[m * 256 + tid];
                #pragma unroll
                for (int l = 0; l < 4; ++l) {
                    const u32 col = (u32)((m * 256 + tid) * 4 + l);
                    l2 += (toKey(v[l]) == T && col < trial) ? 1u : 0u;
                }
            }
            #pragma unroll
            for (int off = 32; off >= 1; off >>= 1) l2 += __shfl_down(l2, off);
            if (lane == 0) wtot[wid] = l2;
            __syncthreads();
            u32 t = 0;
            #pragma unroll
            for (int w = 0; w < 4; ++w) t += wtot[w];
            __syncthreads();
            if (t < needEq) cv = trial;
        }
        const u32 colT = cv;
        #pragma unroll 1
        for (int m = 0; m < 32; ++m) {
            const u32x4 v = xrow[m * 256 + tid];
            #pragma unroll
            for (int l = 0; l < 4; ++l) {
                const u32 k = toKey(v[l]);
                const u32 col = (u32)((m * 256 + tid) * 4 + l);
                if ((k > T) || (k == T && col <= colT)) orowU[col] = v[l];
            }
        }
    }
}

// ---------------- Fallback: R13 single-kernel (proven, 456 us) ----------------
__device__ __forceinline__ u32 blockSum4(u32 v, volatile u32* wt, int lane, int wid)
{
    #pragma unroll
    for (int off = 32; off >= 1; off >>= 1) v += __shfl_down(v, off);
    if (lane == 0) wt[wid] = v;
    __syncthreads();
    u32 t = 0;
    #pragma unroll
    for (int w = 0; w < 4; ++w) t += wt[w];
    __syncthreads();
    return t;
}

__global__ __launch_bounds__(256) void topk_fallback_kernel(
    const float* __restrict__ x, float* __restrict__ out)
{
    __shared__ u32 hist[1024];
    __shared__ u64 candPk[CAPW];
    __shared__ u64 eqPk[EQCAP];
    __shared__ u32 wtot[4];
    __shared__ int sBin;
    __shared__ u32 sAbove, sEqCnt, candN, eqN;

    const int tid  = threadIdx.x;
    const int lane = tid & 63;
    const int wid  = tid >> 6;

    const long long row = blockIdx.x;
    const u32x4* __restrict__ xrow = (const u32x4*)(x + row * (long long)COLS);
    u32x4* __restrict__ orow       = (u32x4*)(out + row * (long long)COLS);
    u32*   __restrict__ orowU      = (u32*)(out + row * (long long)COLS);

    ((u32x4*)hist)[tid] = (u32x4)(0u);
    if (tid == 0) { candN = 0u; eqN = 0u; sBin = -1; }
    __syncthreads();

    #pragma unroll 1
    for (int g = 0; g < 4; ++g) {
        u32x4 v[8];
        #pragma unroll
        for (int j = 0; j < 8; ++j) v[j] = xrow[(g * 8 + j) * 256 + tid];
        #pragma unroll
        for (int j = 0; j < 8; ++j) orow[(g * 8 + j) * 256 + tid] = (u32x4)(0u);
        #pragma unroll
        for (int j = 0; j < 8; ++j) {
            #pragma unroll
            for (int l = 0; l < 4; ++l) {
                const u32 k = v[j][l];
                if ((int)k > (int)THR) {
                    const u32 p = atomicAdd(&candN, 1u);
                    const u32 col = (u32)(((g * 8 + j) * 256 + tid) * 4 + l);
                    if (p < CAPW) candPk[p] = ((u64)k << 32) | (u32)(~col);
                }
            }
        }
    }
    __syncthreads();

    const u32 C = candN;
    bool done = false;

    if (C >= KSEL && C <= CAPW) {
        for (u32 i = tid; i < C; i += 256u) {
            const u32 k = (u32)(candPk[i] >> 32);
            u32 idx = (k - THR) >> 15;
            if (idx > 1023u) idx = 1023u;
            atomicAdd(&hist[idx], 1u);
        }
        __syncthreads();
        {
            const u32x4 h = ((const u32x4*)hist)[tid];
            const u32 ls3 = h[3];
            const u32 ls2 = h[2] + ls3;
            const u32 ls1 = h[1] + ls2;
            const u32 ls0 = h[0] + ls1;
            u32 v = ls0;
            #pragma unroll
            for (int off = 1; off < 64; off <<= 1) {
                const u32 t = __shfl_down(v, off);
                if (lane + off < 64) v += t;
            }
            if (lane == 0) wtot[wid] = v;
            __syncthreads();
            u32 tail = 0u;
            #pragma unroll
            for (int w = 0; w < 4; ++w) if (w > wid) tail += wtot[w];
            const u32 thrTail = tail + (v - ls0);
            const u32 S0 = ls0 + thrTail, S1 = ls1 + thrTail, S2 = ls2 + thrTail,
                      S3 = ls3 + thrTail, S4 = thrTail;
            if (S0 >= KSEL && S1 < KSEL) { sBin = 4*tid+0; sAbove = S1; sEqCnt = h[0]; }
            if (S1 >= KSEL && S2 < KSEL) { sBin = 4*tid+1; sAbove = S2; sEqCnt = h[1]; }
            if (S2 >= KSEL && S3 < KSEL) { sBin = 4*tid+2; sAbove = S3; sEqCnt = h[2]; }
            if (S3 >= KSEL && S4 < KSEL) { sBin = 4*tid+3; sAbove = S4; sEqCnt = h[3]; }
            __syncthreads();
        }
        const u32 b1     = (u32)sBin;
        const u32 need   = KSEL - sAbove;
        const u32 binCnt = sEqCnt;
        if (binCnt <= EQCAP) {
            for (u32 i = tid; i < C; i += 256u) {
                const u32 k = (u32)(candPk[i] >> 32);
                u32 idx = (k - THR) >> 15;
                if (idx > 1023u) idx = 1023u;
                if (idx == b1) { const u32 p = atomicAdd(&eqN, 1u); eqPk[p] = candPk[i]; }
            }
            __syncthreads();
            const u32 E2 = eqN;
            for (u32 i = tid; i < C; i += 256u) {
                const u64 pk = candPk[i];
                const u32 k  = (u32)(pk >> 32);
                u32 idx = (k - THR) >> 15;
                if (idx > 1023u) idx = 1023u;
                bool sel = (idx > b1);
                if (idx == b1) {
                    u32 r = 0;
                    for (u32 q = 0; q < E2; ++q) r += (eqPk[q] > pk) ? 1u : 0u;
                    sel = (r < need);
                }
                if (sel) orowU[~(u32)pk] = k;
            }
            done = true;
        }
    }

    if (!done) {
        u32 pfx = 0u;
        for (int bit = 31; bit >= 0; --bit) {
            const u32 trial = pfx | (1u << bit);
            u32 loc = 0u;
            #pragma unroll 1
            for (int m = 0; m < 32; ++m) {
                const u32x4 v = xrow[m * 256 + tid];
                #pragma unroll
                for (int l = 0; l < 4; ++l) loc += (toKey(v[l]) >= trial) ? 1u : 0u;
            }
            if (blockSum4(loc, wtot, lane, wid) >= KSEL) pfx = trial;
        }
        const u32 T = pfx;
        u32 loc = 0u;
        #pragma unroll 1
        for (int m = 0; m < 32; ++m) {
            const u32x4 v = xrow[m * 256 + tid];
            #pragma unroll
            for (int l = 0; l < 4; ++l) loc += (toKey(v[l]) > T) ? 1u : 0u;
        }
        const u32 needEq = KSEL - blockSum4(loc, wtot, lane, wid);
        u32 cv = 0u;
        for (int bit = 14; bit >= 0; --bit) {
            const u32 trial = cv | (1u << bit);
            u32 l2 = 0u;
            #pragma unroll 1
            for (int m = 0; m < 32; ++m) {
                const u32x4 v = xrow[m * 256 + tid];
                #pragma unroll
                for (int l = 0; l < 4; ++l) {
                    const u32 col = (u32)((m * 256 + tid) * 4 + l);
                    l2 += (toKey(v[l]) == T && col < trial) ? 1u : 0u;
                }
            }
            if (blockSum4(l2, wtot, lane, wid) < needEq) cv = trial;
        }
        const u32 colT = cv;
        #pragma unroll 1
        for (int m = 0; m < 32; ++m) {
            const u32x4 v = xrow[m * 256 + tid];
            #pragma unroll
            for (int l = 0; l < 4; ++l) {
                const u32 k = toKey(v[l]);
                const u32 col = (u32)((m * 256 + tid) * 4 + l);
                if ((k > T) || (k == T && col <= colT)) orowU[col] = v[l];
            }
        }
    }
}

extern "C" void kernel_launch(void* const* d_in, const int* in_sizes, int n_in,
                              void* d_out, int out_size, void* d_ws, size_t ws_size,
                              hipStream_t stream)
{
    (void)n_in; (void)out_size;
    const float* x = (const float*)d_in[0];
    float* out = (float*)d_out;
    const int rows = in_sizes[0] / COLS;
    const u32 totalVec = (u32)((in_sizes[0]) / 4);

    const size_t cntBytes  = (size_t)rows * sizeof(u32);
    const size_t needBytes = cntBytes + (size_t)rows * CAPW * sizeof(u64);

    if (d_ws != nullptr && ws_size >= needBytes) {
        u32* cnt   = (u32*)d_ws;
        u64* lists = (u64*)((char*)d_ws + cntBytes);
        hipMemsetAsync(d_ws, 0, cntBytes, stream);
        stream_compact_kernel<<<dim3(2048), dim3(256), 0, stream>>>(
            (const u32x4*)x, (u32x4*)out, cnt, lists, totalVec);
        select_scatter_kernel<<<dim3(rows), dim3(256), 0, stream>>>(
            (const u32x4*)x, out, cnt, lists);
    } else {
        topk_fallback_kernel<<<dim3(rows), dim3(256), 0, stream>>>(x, out);
    }
}

// Round 15
// 341.686 us; speedup vs baseline: 4.5128x; 4.5128x over previous
//
#include <hip/hip_runtime.h>

// TopK-and-scatter: out[r,c] = x[r,c] if x[r,c] is among the top-64 of row r
// (ties at threshold broken by LOWEST column index, matching lax.top_k), else 0.
// R15: direction-split two-kernel pipeline, NO global atomics.
// K1 (read-only): one block per row; stream row, append (int)bits > bits(2.0)
// candidates (packed (bits<<32)|~col) to an LDS list via LDS atomics, dump
// list + count to d_ws with plain coalesced stores.
// K2 (write-only): one block per row; load candidate list -> LDS, issue the
// full row of zero-stores, run select (mini-hist -> suffix scan -> exact
// packed-key rank; R13-proven) under lgkm-only barriers so zero-stores stay
// in flight; then vmcnt(0)+syncthreads (R9-proven ordering) and scatter the
// <=64 selected dwords. Exact slow path in K2 (C<64 / C>CAP / fat bin)
// re-reads the row — unreachable for N(0,1) data (count(x>2) in [646,844],
// cap 1024), correct for any input. Fallback: proven R13 single kernel if
// ws_size too small.

typedef unsigned int u32;
typedef unsigned long long u64;
typedef u32 u32x4 __attribute__((ext_vector_type(4)));

#define COLS   32768
#define KSEL   64u
#define THR    0x40000000u  // bits of 2.0f
#define CAPW   1024u
#define EQCAP  256u

__device__ __forceinline__ u32 toKey(u32 b) {
    return b ^ ((u32)((int)b >> 31) | 0x80000000u);
}

// LDS-only barrier: orders LDS ops across the block WITHOUT draining vmcnt
// (in-flight global stores survive). R6/R7-validated.
__device__ __forceinline__ void ldsBarrier() {
    asm volatile("s_waitcnt lgkmcnt(0)" ::: "memory");
    __builtin_amdgcn_s_barrier();
    asm volatile("" ::: "memory");
}

// ---------------- K1: read-only stream + LDS compact + dump ----------------
__global__ __launch_bounds__(256) void collect_kernel(
    const u32x4* __restrict__ x, u32* __restrict__ cnt, u64* __restrict__ lists)
{
    __shared__ u64 cpk[CAPW];             // 8 KB
    __shared__ u32 candN;

    const int tid = threadIdx.x;
    const u32 row = blockIdx.x;
    const u32x4* __restrict__ xrow = x + (u64)row * (COLS / 4);

    if (tid == 0) candN = 0u;
    __syncthreads();

    #pragma unroll 1
    for (int g = 0; g < 4; ++g) {
        u32x4 v[8];
        #pragma unroll
        for (int j = 0; j < 8; ++j) v[j] = xrow[(g * 8 + j) * 256 + tid];
        #pragma unroll
        for (int j = 0; j < 8; ++j) {
            #pragma unroll
            for (int l = 0; l < 4; ++l) {
                const u32 k = v[j][l];
                if ((int)k > (int)THR) {
                    const u32 p = atomicAdd(&candN, 1u);   // LDS atomic
                    const u32 col = (u32)(((g * 8 + j) * 256 + tid) * 4 + l);
                    if (p < CAPW) cpk[p] = ((u64)k << 32) | (u32)(~col);
                }
            }
        }
    }
    __syncthreads();

    const u32 C  = candN;
    const u32 Cw = (C < CAPW) ? C : CAPW;
    for (u32 i = tid; i < Cw; i += 256u)
        lists[(u64)row * CAPW + i] = cpk[i];               // coalesced 8B stores
    if (tid == 0) cnt[row] = C;
}

// ---------------- K2: zero-write + select (hidden) + scatter ----------------
__global__ __launch_bounds__(256) void write_select_kernel(
    const u32x4* __restrict__ x, float* __restrict__ out,
    const u32* __restrict__ cnt, const u64* __restrict__ lists)
{
    __shared__ u64 cpk[CAPW];             // 8 KB
    __shared__ u64 eqPk[EQCAP];           // 2 KB
    __shared__ u32 hist[1024];            // 4 KB
    __shared__ u32 wtot[4];
    __shared__ int sBin;
    __shared__ u32 sAbove, sEqCnt, eqN;

    const int tid  = threadIdx.x;
    const int lane = tid & 63;
    const int wid  = tid >> 6;
    const u32 row  = blockIdx.x;

    const u32x4* __restrict__ xrow  = x + (u64)row * (COLS / 4);
    u32x4* __restrict__ orow        = (u32x4*)(out + (u64)row * COLS);
    u32*   __restrict__ orowU       = (u32*)(out + (u64)row * COLS);

    // issue list loads first (4 u64/thread covers CAPW=1024)
    const u32 C = cnt[row];
    u64 myl[4];
    #pragma unroll
    for (int j = 0; j < 4; ++j)
        myl[j] = lists[(u64)row * CAPW + (u32)j * 256u + tid];

    // issue the FULL row of zero-stores (stay in flight through select)
    #pragma unroll
    for (int j = 0; j < 8; ++j) orow[j * 256 + tid] = (u32x4)(0u);

    // stash list + init select state (compiler waits the loads, not the stores)
    ((u32x4*)hist)[tid] = (u32x4)(0u);
    if (tid == 0) { sBin = -1; eqN = 0u; }
    #pragma unroll
    for (int j = 0; j < 4; ++j) cpk[(u32)j * 256u + tid] = myl[j];
    ldsBarrier();                          // A: cpk + zeros visible (lgkm only)

    bool fast = (C >= KSEL && C <= CAPW);
    bool done = false;

    if (fast) {
        // mini histogram over candidates: bins (bits-THR)>>15, clamped
        for (u32 i = tid; i < C; i += 256u) {
            const u32 k = (u32)(cpk[i] >> 32);
            u32 idx = (k - THR) >> 15;
            if (idx > 1023u) idx = 1023u;
            atomicAdd(&hist[idx], 1u);
        }
        ldsBarrier();                      // B: hist ready
        // suffix scan: thread owns bins [4*tid, 4*tid+4)
        {
            const u32x4 h = ((const u32x4*)hist)[tid];
            const u32 ls3 = h[3];
            const u32 ls2 = h[2] + ls3;
            const u32 ls1 = h[1] + ls2;
            const u32 ls0 = h[0] + ls1;
            u32 v = ls0;
            #pragma unroll
            for (int off = 1; off < 64; off <<= 1) {
                const u32 t = __shfl_down(v, off);
                if (lane + off < 64) v += t;
            }
            if (lane == 0) wtot[wid] = v;
            ldsBarrier();                  // C: wtot ready
            u32 tail = 0u;
            #pragma unroll
            for (int w = 0; w < 4; ++w) if (w > wid) tail += wtot[w];
            const u32 thrTail = tail + (v - ls0);
            const u32 S0 = ls0 + thrTail, S1 = ls1 + thrTail,
                      S2 = ls2 + thrTail, S3 = ls3 + thrTail, S4 = thrTail;
            if (S0 >= KSEL && S1 < KSEL) { sBin = 4*tid+0; sAbove = S1; sEqCnt = h[0]; }
            if (S1 >= KSEL && S2 < KSEL) { sBin = 4*tid+1; sAbove = S2; sEqCnt = h[1]; }
            if (S2 >= KSEL && S3 < KSEL) { sBin = 4*tid+2; sAbove = S3; sEqCnt = h[2]; }
            if (S3 >= KSEL && S4 < KSEL) { sBin = 4*tid+3; sAbove = S4; sEqCnt = h[3]; }
            ldsBarrier();                  // D: crossing known (C >= KSEL)
        }
        const u32 b1     = (u32)sBin;
        const u32 need   = KSEL - sAbove;
        const u32 binCnt = sEqCnt;

        if (binCnt <= EQCAP) {
            for (u32 i = tid; i < C; i += 256u) {
                const u32 k = (u32)(cpk[i] >> 32);
                u32 idx = (k - THR) >> 15;
                if (idx > 1023u) idx = 1023u;
                if (idx == b1) { const u32 p = atomicAdd(&eqN, 1u); eqPk[p] = cpk[i]; }
            }
            ldsBarrier();                  // E: eq list ready
            const u32 E2 = eqN;
            // drain zero-stores block-wide, then scatter (R9-proven ordering)
            asm volatile("s_waitcnt vmcnt(0)" ::: "memory");
            __syncthreads();
            for (u32 i = tid; i < C; i += 256u) {
                const u64 pk = cpk[i];
                const u32 k  = (u32)(pk >> 32);
                u32 idx = (k - THR) >> 15;
                if (idx > 1023u) idx = 1023u;
                bool sel = (idx > b1);
                if (idx == b1) {
                    u32 r = 0;
                    for (u32 q = 0; q < E2; ++q) r += (eqPk[q] > pk) ? 1u : 0u;
                    sel = (r < need);
                }
                if (sel) orowU[~(u32)pk] = k;
            }
            done = true;
        }
    }

    if (!done) {
        // ---- exact slow path: stream row, bitwise searches, scatter ----
        // (__syncthreads here drains the zero-stores -> ordering safe)
        u32 pfx = 0u;
        for (int bit = 31; bit >= 0; --bit) {
            const u32 trial = pfx | (1u << bit);
            u32 loc = 0u;
            #pragma unroll 1
            for (int m = 0; m < 32; ++m) {
                const u32x4 v = xrow[m * 256 + tid];
                #pragma unroll
                for (int l = 0; l < 4; ++l) loc += (toKey(v[l]) >= trial) ? 1u : 0u;
            }
            #pragma unroll
            for (int off = 32; off >= 1; off >>= 1) loc += __shfl_down(loc, off);
            if (lane == 0) wtot[wid] = loc;
            __syncthreads();
            u32 t = 0;
            #pragma unroll
            for (int w = 0; w < 4; ++w) t += wtot[w];
            __syncthreads();
            if (t >= KSEL) pfx = trial;
        }
        const u32 T = pfx;
        u32 loc = 0u;
        #pragma unroll 1
        for (int m = 0; m < 32; ++m) {
            const u32x4 v = xrow[m * 256 + tid];
            #pragma unroll
            for (int l = 0; l < 4; ++l) loc += (toKey(v[l]) > T) ? 1u : 0u;
        }
        #pragma unroll
        for (int off = 32; off >= 1; off >>= 1) loc += __shfl_down(loc, off);
        if (lane == 0) wtot[wid] = loc;
        __syncthreads();
        u32 above = 0;
        #pragma unroll
        for (int w = 0; w < 4; ++w) above += wtot[w];
        __syncthreads();
        const u32 needEq = KSEL - above;
        u32 cv = 0u;
        for (int bit = 14; bit >= 0; --bit) {
            const u32 trial = cv | (1u << bit);
            u32 l2 = 0u;
            #pragma unroll 1
            for (int m = 0; m < 32; ++m) {
                const u32x4 v = xrow[m * 256 + tid];
                #pragma unroll
                for (int l = 0; l < 4; ++l) {
                    const u32 col = (u32)((m * 256 + tid) * 4 + l);
                    l2 += (toKey(v[l]) == T && col < trial) ? 1u : 0u;
                }
            }
            #pragma unroll
            for (int off = 32; off >= 1; off >>= 1) l2 += __shfl_down(l2, off);
            if (lane == 0) wtot[wid] = l2;
            __syncthreads();
            u32 t = 0;
            #pragma unroll
            for (int w = 0; w < 4; ++w) t += wtot[w];
            __syncthreads();
            if (t < needEq) cv = trial;
        }
        const u32 colT = cv;
        #pragma unroll 1
        for (int m = 0; m < 32; ++m) {
            const u32x4 v = xrow[m * 256 + tid];
            #pragma unroll
            for (int l = 0; l < 4; ++l) {
                const u32 k = toKey(v[l]);
                const u32 col = (u32)((m * 256 + tid) * 4 + l);
                if ((k > T) || (k == T && col <= colT)) orowU[col] = v[l];
            }
        }
    }
}

// ---------------- Fallback: R13 single-kernel (proven 456 us) ----------------
__device__ __forceinline__ u32 blockSum4(u32 v, volatile u32* wt, int lane, int wid)
{
    #pragma unroll
    for (int off = 32; off >= 1; off >>= 1) v += __shfl_down(v, off);
    if (lane == 0) wt[wid] = v;
    __syncthreads();
    u32 t = 0;
    #pragma unroll
    for (int w = 0; w < 4; ++w) t += wt[w];
    __syncthreads();
    return t;
}

__global__ __launch_bounds__(256) void topk_fallback_kernel(
    const float* __restrict__ x, float* __restrict__ out)
{
    __shared__ u32 hist[1024];
    __shared__ u64 candPk[CAPW];
    __shared__ u64 eqPk[EQCAP];
    __shared__ u32 wtot[4];
    __shared__ int sBin;
    __shared__ u32 sAbove, sEqCnt, candN, eqN;

    const int tid  = threadIdx.x;
    const int lane = tid & 63;
    const int wid  = tid >> 6;

    const long long row = blockIdx.x;
    const u32x4* __restrict__ xrow = (const u32x4*)(x + row * (long long)COLS);
    u32x4* __restrict__ orow       = (u32x4*)(out + row * (long long)COLS);
    u32*   __restrict__ orowU      = (u32*)(out + row * (long long)COLS);

    ((u32x4*)hist)[tid] = (u32x4)(0u);
    if (tid == 0) { candN = 0u; eqN = 0u; sBin = -1; }
    __syncthreads();

    #pragma unroll 1
    for (int g = 0; g < 4; ++g) {
        u32x4 v[8];
        #pragma unroll
        for (int j = 0; j < 8; ++j) v[j] = xrow[(g * 8 + j) * 256 + tid];
        #pragma unroll
        for (int j = 0; j < 8; ++j) orow[(g * 8 + j) * 256 + tid] = (u32x4)(0u);
        #pragma unroll
        for (int j = 0; j < 8; ++j) {
            #pragma unroll
            for (int l = 0; l < 4; ++l) {
                const u32 k = v[j][l];
                if ((int)k > (int)THR) {
                    const u32 p = atomicAdd(&candN, 1u);
                    const u32 col = (u32)(((g * 8 + j) * 256 + tid) * 4 + l);
                    if (p < CAPW) candPk[p] = ((u64)k << 32) | (u32)(~col);
                }
            }
        }
    }
    __syncthreads();

    const u32 C = candN;
    bool done = false;

    if (C >= KSEL && C <= CAPW) {
        for (u32 i = tid; i < C; i += 256u) {
            const u32 k = (u32)(candPk[i] >> 32);
            u32 idx = (k - THR) >> 15;
            if (idx > 1023u) idx = 1023u;
            atomicAdd(&hist[idx], 1u);
        }
        __syncthreads();
        {
            const u32x4 h = ((const u32x4*)hist)[tid];
            const u32 ls3 = h[3];
            const u32 ls2 = h[2] + ls3;
            const u32 ls1 = h[1] + ls2;
            const u32 ls0 = h[0] + ls1;
            u32 v = ls0;
            #pragma unroll
            for (int off = 1; off < 64; off <<= 1) {
                const u32 t = __shfl_down(v, off);
                if (lane + off < 64) v += t;
            }
            if (lane == 0) wtot[wid] = v;
            __syncthreads();
            u32 tail = 0u;
            #pragma unroll
            for (int w = 0; w < 4; ++w) if (w > wid) tail += wtot[w];
            const u32 thrTail = tail + (v - ls0);
            const u32 S0 = ls0 + thrTail, S1 = ls1 + thrTail, S2 = ls2 + thrTail,
                      S3 = ls3 + thrTail, S4 = thrTail;
            if (S0 >= KSEL && S1 < KSEL) { sBin = 4*tid+0; sAbove = S1; sEqCnt = h[0]; }
            if (S1 >= KSEL && S2 < KSEL) { sBin = 4*tid+1; sAbove = S2; sEqCnt = h[1]; }
            if (S2 >= KSEL && S3 < KSEL) { sBin = 4*tid+2; sAbove = S3; sEqCnt = h[2]; }
            if (S3 >= KSEL && S4 < KSEL) { sBin = 4*tid+3; sAbove = S4; sEqCnt = h[3]; }
            __syncthreads();
        }
        const u32 b1     = (u32)sBin;
        const u32 need   = KSEL - sAbove;
        const u32 binCnt = sEqCnt;
        if (binCnt <= EQCAP) {
            for (u32 i = tid; i < C; i += 256u) {
                const u32 k = (u32)(candPk[i] >> 32);
                u32 idx = (k - THR) >> 15;
                if (idx > 1023u) idx = 1023u;
                if (idx == b1) { const u32 p = atomicAdd(&eqN, 1u); eqPk[p] = candPk[i]; }
            }
            __syncthreads();
            const u32 E2 = eqN;
            for (u32 i = tid; i < C; i += 256u) {
                const u64 pk = candPk[i];
                const u32 k  = (u32)(pk >> 32);
                u32 idx = (k - THR) >> 15;
                if (idx > 1023u) idx = 1023u;
                bool sel = (idx > b1);
                if (idx == b1) {
                    u32 r = 0;
                    for (u32 q = 0; q < E2; ++q) r += (eqPk[q] > pk) ? 1u : 0u;
                    sel = (r < need);
                }
                if (sel) orowU[~(u32)pk] = k;
            }
            done = true;
        }
    }

    if (!done) {
        u32 pfx = 0u;
        for (int bit = 31; bit >= 0; --bit) {
            const u32 trial = pfx | (1u << bit);
            u32 loc = 0u;
            #pragma unroll 1
            for (int m = 0; m < 32; ++m) {
                const u32x4 v = xrow[m * 256 + tid];
                #pragma unroll
                for (int l = 0; l < 4; ++l) loc += (toKey(v[l]) >= trial) ? 1u : 0u;
            }
            if (blockSum4(loc, wtot, lane, wid) >= KSEL) pfx = trial;
        }
        const u32 T = pfx;
        u32 loc = 0u;
        #pragma unroll 1
        for (int m = 0; m < 32; ++m) {
            const u32x4 v = xrow[m * 256 + tid];
            #pragma unroll
            for (int l = 0; l < 4; ++l) loc += (toKey(v[l]) > T) ? 1u : 0u;
        }
        const u32 needEq = KSEL - blockSum4(loc, wtot, lane, wid);
        u32 cv = 0u;
        for (int bit = 14; bit >= 0; --bit) {
            const u32 trial = cv | (1u << bit);
            u32 l2 = 0u;
            #pragma unroll 1
            for (int m = 0; m < 32; ++m) {
                const u32x4 v = xrow[m * 256 + tid];
                #pragma unroll
                for (int l = 0; l < 4; ++l) {
                    const u32 col = (u32)((m * 256 + tid) * 4 + l);
                    l2 += (toKey(v[l]) == T && col < trial) ? 1u : 0u;
                }
            }
            if (blockSum4(l2, wtot, lane, wid) < needEq) cv = trial;
        }
        const u32 colT = cv;
        #pragma unroll 1
        for (int m = 0; m < 32; ++m) {
            const u32x4 v = xrow[m * 256 + tid];
            #pragma unroll
            for (int l = 0; l < 4; ++l) {
                const u32 k = toKey(v[l]);
                const u32 col = (u32)((m * 256 + tid) * 4 + l);
                if ((k > T) || (k == T && col <= colT)) orowU[col] = v[l];
            }
        }
    }
}

extern "C" void kernel_launch(void* const* d_in, const int* in_sizes, int n_in,
                              void* d_out, int out_size, void* d_ws, size_t ws_size,
                              hipStream_t stream)
{
    (void)n_in; (void)out_size;
    const float* x = (const float*)d_in[0];
    float* out = (float*)d_out;
    const int rows = in_sizes[0] / COLS;

    const size_t cntBytes  = (size_t)rows * sizeof(u32);        // 32 KB
    const size_t needBytes = cntBytes + (size_t)rows * CAPW * sizeof(u64);

    if (d_ws != nullptr && ws_size >= needBytes) {
        u32* cnt   = (u32*)d_ws;
        u64* lists = (u64*)((char*)d_ws + cntBytes);
        collect_kernel<<<dim3(rows), dim3(256), 0, stream>>>(
            (const u32x4*)x, cnt, lists);
        write_select_kernel<<<dim3(rows), dim3(256), 0, stream>>>(
            (const u32x4*)x, out, cnt, lists);
    } else {
        topk_fallback_kernel<<<dim3(rows), dim3(256), 0, stream>>>(x, out);
    }
}